// Round 1
// baseline (247.838 us; speedup 1.0000x reference)
//
#include <hip/hip_runtime.h>
#include <math.h>

#define NN 50000
#define NE 800000
#define DD 128
#define NBUCK 196        // ceil(NN/256) buckets of 256 nodes
#define PTILE 4096       // edges per partition block
#define PBLOCKS 196      // ceil(NE/PTILE)
#define CONVB 6250       // NN*DD/4/256

typedef unsigned short u16;
typedef short s8v __attribute__((ext_vector_type(8)));    // 8 bf16 (4 VGPRs)
typedef float f16v __attribute__((ext_vector_type(16)));  // 16 fp32 acc

__device__ __forceinline__ u16 f2bf(float f) {  // RNE fp32->bf16
    unsigned u = __float_as_uint(f);
    return (u16)((u + 0x7FFFu + ((u >> 16) & 1u)) >> 16);
}
__device__ __forceinline__ float bflo(unsigned u) { return __uint_as_float(u << 16); }
__device__ __forceinline__ float bfhi(unsigned u) { return __uint_as_float(u & 0xFFFF0000u); }

// ---- fused prep: x->bf16 conv | 3x weight pack | zero bcnt ----
// pack order: out[((c*4+n)*64+l)*8+j] = Wcat[col=n*32+(l&31)][k=c*16+(l>>5)*8+j]
__device__ __forceinline__ void pack_one(const float* __restrict__ Wl,
                                         const float* __restrict__ Wr,
                                         bool two, int o, u16* __restrict__ out) {
    int j = o & 7;
    int l = (o >> 3) & 63;
    int cn = o >> 9;
    int n = cn & 3;
    int c = cn >> 2;
    int colj = n * 32 + (l & 31);
    int k = c * 16 + (l >> 5) * 8 + j;
    float v;
    if (two) v = (k < DD) ? Wl[colj * DD + k] : Wr[colj * DD + (k - DD)];
    else     v = Wl[colj * DD + k];
    out[o] = f2bf(v);
}

__global__ __launch_bounds__(256) void prep_kernel(
        const float4* __restrict__ x4, ushort4* __restrict__ hb0,
        const float* __restrict__ Wl, const float* __restrict__ Wr,
        const float* __restrict__ W,
        u16* __restrict__ Bpk0, u16* __restrict__ Bpk1, u16* __restrict__ Bpkf,
        int* __restrict__ bcnt) {
    int bid = blockIdx.x;
    int tid = threadIdx.x;
    if (bid < CONVB) {
        int i = bid * 256 + tid;
        float4 v = x4[i];
        ushort4 o;
        o.x = f2bf(v.x); o.y = f2bf(v.y); o.z = f2bf(v.z); o.w = f2bf(v.w);
        hb0[i] = o;
    } else if (bid < CONVB + 128) {
        pack_one(Wl, Wr, true, (bid - CONVB) * 256 + tid, Bpk0);
    } else if (bid < CONVB + 256) {
        pack_one(Wl + DD * DD, Wr + DD * DD, true, (bid - CONVB - 128) * 256 + tid, Bpk1);
    } else if (bid < CONVB + 320) {
        pack_one(W, W, false, (bid - CONVB - 256) * 256 + tid, Bpkf);
    } else {
        if (tid < NBUCK) bcnt[tid] = 0;
    }
}

// ---- Phase A1: coarse bucket histogram ----
__global__ __launch_bounds__(256) void bucket_hist(const int* __restrict__ ei,
                                                   int* __restrict__ bcnt) {
    __shared__ int h[NBUCK];
    for (int i = threadIdx.x; i < NBUCK; i += 256) h[i] = 0;
    __syncthreads();
    int e0 = blockIdx.x * PTILE;
#pragma unroll
    for (int i = 0; i < 16; i++) {
        int e = e0 + i * 256 + threadIdx.x;
        if (e < NE) atomicAdd(&h[ei[NE + e] >> 8], 1);
    }
    __syncthreads();
    for (int i = threadIdx.x; i < NBUCK; i += 256)
        if (h[i]) atomicAdd(&bcnt[i], h[i]);
}

// ---- Phase A2: scan bucket counts -> bases + cursors ----
__global__ __launch_bounds__(256) void bucket_scan(const int* __restrict__ bcnt,
                                                   int* __restrict__ bbase,
                                                   int* __restrict__ bcur,
                                                   int* __restrict__ rowptr) {
    __shared__ int s[256];
    int t = threadIdx.x;
    int v = (t < NBUCK) ? bcnt[t] : 0;
    s[t] = v;
    __syncthreads();
    for (int o = 1; o < 256; o <<= 1) {
        int u = (t >= o) ? s[t - o] : 0;
        __syncthreads();
        s[t] += u;
        __syncthreads();
    }
    int ex = s[t] - v;
    if (t < NBUCK) { bbase[t] = ex; bcur[t] = ex; }
    if (t == 0) rowptr[NN] = NE;
}

// ---- Phase A3: partition edges into bucket-contiguous packed array ----
__global__ __launch_bounds__(256) void bucket_partition(const int* __restrict__ ei,
                                                        int* __restrict__ bcur,
                                                        unsigned* __restrict__ packed) {
    __shared__ int h[NBUCK];
    __shared__ int base[NBUCK];
    int t = threadIdx.x;
    for (int i = t; i < NBUCK; i += 256) h[i] = 0;
    __syncthreads();
    int e0 = blockIdx.x * PTILE;
    int dsts[16], srcs[16];
#pragma unroll
    for (int i = 0; i < 16; i++) {
        int e = e0 + i * 256 + t;
        if (e < NE) {
            dsts[i] = ei[NE + e];
            srcs[i] = ei[e];
            atomicAdd(&h[dsts[i] >> 8], 1);
        } else dsts[i] = -1;
    }
    __syncthreads();
    for (int i = t; i < NBUCK; i += 256) {
        int c = h[i];
        base[i] = c ? atomicAdd(&bcur[i], c) : 0;
    }
    __syncthreads();
    for (int i = t; i < NBUCK; i += 256) h[i] = 0;  // reuse as local cursor
    __syncthreads();
#pragma unroll
    for (int i = 0; i < 16; i++) {
        if (dsts[i] >= 0) {
            int bk = dsts[i] >> 8;
            int r = atomicAdd(&h[bk], 1);
            packed[base[bk] + r] = (unsigned)srcs[i] | ((unsigned)(dsts[i] & 255) << 16);
        }
    }
}

// ---- Phase B: per-bucket counting sort -> rowptr + col ----
__global__ __launch_bounds__(256) void bucket_csr(const unsigned* __restrict__ packed,
                                                  const int* __restrict__ bcnt,
                                                  const int* __restrict__ bbase,
                                                  int* __restrict__ rowptr,
                                                  int* __restrict__ col) {
    __shared__ int deg[256];
    __shared__ int off[256];
    int bk = blockIdx.x;
    int cnt = bcnt[bk], base = bbase[bk];
    int t = threadIdx.x;
    deg[t] = 0;
    __syncthreads();
    for (int i = t; i < cnt; i += 256) atomicAdd(&deg[packed[base + i] >> 16], 1);
    __syncthreads();
    int v = deg[t];
    off[t] = v;
    __syncthreads();
    for (int o = 1; o < 256; o <<= 1) {
        int u = (t >= o) ? off[t - o] : 0;
        __syncthreads();
        off[t] += u;
        __syncthreads();
    }
    int ex = off[t] - v;
    int node = (bk << 8) + t;
    if (node < NN) rowptr[node] = base + ex;
    deg[t] = ex;  // reuse as cursor
    __syncthreads();
    for (int i = t; i < cnt; i += 256) {
        unsigned p = packed[base + i];
        int dl = p >> 16;
        int r = atomicAdd(&deg[dl], 1);
        col[base + r] = (int)(p & 0xFFFFu);
    }
}

// ---- helpers for segmented max ----
__device__ __forceinline__ void vmax8(float* m, uint4 v) {
    m[0] = fmaxf(m[0], bflo(v.x)); m[1] = fmaxf(m[1], bfhi(v.x));
    m[2] = fmaxf(m[2], bflo(v.y)); m[3] = fmaxf(m[3], bfhi(v.y));
    m[4] = fmaxf(m[4], bflo(v.z)); m[5] = fmaxf(m[5], bfhi(v.z));
    m[6] = fmaxf(m[6], bflo(v.w)); m[7] = fmaxf(m[7], bfhi(v.w));
}

// ================= fused layer: agg(LDS) -> MFMA(+optional 2nd GEMM) ==============
// Per block: 128 rows. Phase 1: segmented bf16 max for those rows into a 32KB LDS
// tile (256B rows, XOR-swizzled by ((row&7)<<4) to kill the D=128 32-way bank
// conflict on ds_read_b128). Phase 2: MFMA K=256 with A = [LDS agg | global hsrc],
// B from L2 (Bpk). FINAL: relu'd bf16 acc goes BACK into the same LDS tile (it is
// exactly the A-operand of the 128x128 final linear for these rows), second K=128
// MFMA with Bpkf, fp32 out. hb0-L1out / aggb round-trips never touch memory.
template<bool FINAL>
__global__ __launch_bounds__(256) void fused_layer(
        const u16* __restrict__ hsrc,
        const int* __restrict__ rowptr,
        const int* __restrict__ col,
        const u16* __restrict__ Bpk,
        const float* __restrict__ bias,
        const u16* __restrict__ Bpkf,
        const float* __restrict__ bfin,
        void* __restrict__ outv) {
    __shared__ u16 As[128 * 128];  // 32 KB
    char* Ab = (char*)As;
    int tid = threadIdx.x;
    int row0 = blockIdx.x * 128;
    const uint4* xb4 = (const uint4*)hsrc;

    // ---- phase 1: aggregation into LDS, 16 lanes/node, 8 rounds ----
    {
        int j = tid & 15;
        int nl0 = tid >> 4;
        for (int p = 0; p < 8; p++) {
            int rl = (p << 4) + nl0;
            int node = row0 + rl;
            uint4 o = make_uint4(0u, 0u, 0u, 0u);
            if (node < NN) {
                int s0 = rowptr[node], s1 = rowptr[node + 1];
                if (s0 < s1) {
                    float m0[8], m1[8], m2[8], m3[8];
#pragma unroll
                    for (int q = 0; q < 8; q++) { m0[q] = m1[q] = m2[q] = m3[q] = -INFINITY; }
                    int i = s0;
                    for (; i + 8 <= s1; i += 8) {
                        int c0 = col[i],     c1 = col[i + 1], c2 = col[i + 2], c3 = col[i + 3];
                        int c4 = col[i + 4], c5 = col[i + 5], c6 = col[i + 6], c7 = col[i + 7];
                        uint4 v0 = xb4[(size_t)c0 * 16 + j];
                        uint4 v1 = xb4[(size_t)c1 * 16 + j];
                        uint4 v2 = xb4[(size_t)c2 * 16 + j];
                        uint4 v3 = xb4[(size_t)c3 * 16 + j];
                        uint4 v4 = xb4[(size_t)c4 * 16 + j];
                        uint4 v5 = xb4[(size_t)c5 * 16 + j];
                        uint4 v6 = xb4[(size_t)c6 * 16 + j];
                        uint4 v7 = xb4[(size_t)c7 * 16 + j];
                        vmax8(m0, v0); vmax8(m1, v1); vmax8(m2, v2); vmax8(m3, v3);
                        vmax8(m0, v4); vmax8(m1, v5); vmax8(m2, v6); vmax8(m3, v7);
                    }
                    for (; i + 4 <= s1; i += 4) {
                        int c0 = col[i], c1 = col[i + 1], c2 = col[i + 2], c3 = col[i + 3];
                        uint4 v0 = xb4[(size_t)c0 * 16 + j];
                        uint4 v1 = xb4[(size_t)c1 * 16 + j];
                        uint4 v2 = xb4[(size_t)c2 * 16 + j];
                        uint4 v3 = xb4[(size_t)c3 * 16 + j];
                        vmax8(m0, v0); vmax8(m1, v1); vmax8(m2, v2); vmax8(m3, v3);
                    }
                    for (; i < s1; i++) {
                        uint4 v = xb4[(size_t)col[i] * 16 + j];
                        vmax8(m0, v);
                    }
#pragma unroll
                    for (int q = 0; q < 8; q++)
                        m0[q] = fmaxf(fmaxf(m0[q], m1[q]), fmaxf(m2[q], m3[q]));
                    // exact bf16 values -> pack by truncation
                    o.x = (__float_as_uint(m0[0]) >> 16) | (__float_as_uint(m0[1]) & 0xFFFF0000u);
                    o.y = (__float_as_uint(m0[2]) >> 16) | (__float_as_uint(m0[3]) & 0xFFFF0000u);
                    o.z = (__float_as_uint(m0[4]) >> 16) | (__float_as_uint(m0[5]) & 0xFFFF0000u);
                    o.w = (__float_as_uint(m0[6]) >> 16) | (__float_as_uint(m0[7]) & 0xFFFF0000u);
                }
            }
            *(uint4*)(Ab + rl * 256 + ((j << 4) ^ ((rl & 7) << 4))) = o;
        }
    }
    __syncthreads();

    // ---- phase 2: MFMA, A = [LDS agg | global hsrc], K=256 ----
    int wt = tid >> 6;
    int lane = tid & 63;
    int arl = wt * 32 + (lane & 31);           // local A row
    int rg = row0 + arl;
    if (rg > NN - 1) rg = NN - 1;              // clamp OOB global loads
    int koff = (lane >> 5) * 8;
    int swz = (arl & 7) << 4;
    const s8v* Bv = (const s8v*)Bpk;

    f16v acc[4];
#pragma unroll
    for (int n = 0; n < 4; n++) acc[n] = (f16v)(0.0f);

#pragma unroll
    for (int c = 0; c < 16; c++) {
        s8v a;
        if (c < 8)
            a = *(const s8v*)(Ab + arl * 256 + (((c * 16 + koff) * 2) ^ swz));
        else
            a = *(const s8v*)(hsrc + (size_t)rg * DD + (c - 8) * 16 + koff);
#pragma unroll
        for (int n = 0; n < 4; n++) {
            s8v b = Bv[(c * 4 + n) * 64 + lane];
            acc[n] = __builtin_amdgcn_mfma_f32_32x32x16_bf16(a, b, acc[n], 0, 0, 0);
        }
    }

    // epilogue: C/D layout col=lane&31, row=(reg&3)+8*(reg>>2)+4*(lane>>5)
    int rowadd = 4 * (lane >> 5);
    if constexpr (!FINAL) {
        u16* hdst = (u16*)outv;
#pragma unroll
        for (int n = 0; n < 4; n++) {
            int colj = n * 32 + (lane & 31);
            float bj = bias[colj];
#pragma unroll
            for (int r = 0; r < 16; r++) {
                int row = row0 + wt * 32 + (r & 3) + 8 * (r >> 2) + rowadd;
                if (row < NN)
                    hdst[(size_t)row * DD + colj] = f2bf(fmaxf(acc[n][r] + bj, 0.0f));
            }
        }
    } else {
        // relu'd bf16 acc -> LDS (reuse As; it is exactly the A of the final GEMM)
        __syncthreads();  // all waves done reading As
#pragma unroll
        for (int n = 0; n < 4; n++) {
            int colj = n * 32 + (lane & 31);
            float bj = bias[colj];
#pragma unroll
            for (int r = 0; r < 16; r++) {
                int rloc = wt * 32 + (r & 3) + 8 * (r >> 2) + rowadd;
                float v = fmaxf(acc[n][r] + bj, 0.0f);
                *(u16*)(Ab + rloc * 256 + ((colj * 2) ^ ((rloc & 7) << 4))) = f2bf(v);
            }
        }
        __syncthreads();
        // second GEMM: K=128 from LDS, B = Bpkf
        const s8v* Bvf = (const s8v*)Bpkf;
        f16v acc2[4];
#pragma unroll
        for (int n = 0; n < 4; n++) acc2[n] = (f16v)(0.0f);
#pragma unroll
        for (int c = 0; c < 8; c++) {
            s8v a = *(const s8v*)(Ab + arl * 256 + (((c * 16 + koff) * 2) ^ swz));
#pragma unroll
            for (int n = 0; n < 4; n++) {
                s8v b = Bvf[(c * 4 + n) * 64 + lane];
                acc2[n] = __builtin_amdgcn_mfma_f32_32x32x16_bf16(a, b, acc2[n], 0, 0, 0);
            }
        }
        float* fout = (float*)outv;
#pragma unroll
        for (int n = 0; n < 4; n++) {
            int colj = n * 32 + (lane & 31);
            float bj = bfin[colj];
#pragma unroll
            for (int r = 0; r < 16; r++) {
                int row = row0 + wt * 32 + (r & 3) + 8 * (r >> 2) + rowadd;
                if (row < NN)
                    fout[(size_t)row * DD + colj] = acc2[n][r] + bj;
            }
        }
    }
}

extern "C" void kernel_launch(void* const* d_in, const int* in_sizes, int n_in,
                              void* d_out, int out_size, void* d_ws, size_t ws_size,
                              hipStream_t stream) {
    const float* x  = (const float*)d_in[0];
    const int*   ei = (const int*)d_in[1];
    const float* Wl = (const float*)d_in[2];
    const float* bl = (const float*)d_in[3];
    const float* Wr = (const float*)d_in[4];
    const float* W  = (const float*)d_in[5];
    const float* b  = (const float*)d_in[6];
    float* out = (float*)d_out;

    // ws layout (16B-aligned chunks) — aggb slot retained but unused
    u16* aggb = (u16*)d_ws;                         // NN*DD bf16 (unused)
    u16* hb0  = aggb + (size_t)NN * DD;             // NN*DD
    u16* hb1  = hb0 + (size_t)NN * DD;              // NN*DD
    u16* Bpk0 = hb1 + (size_t)NN * DD;              // 32768
    u16* Bpk1 = Bpk0 + 32768;                       // 32768
    u16* Bpkf = Bpk1 + 32768;                       // 16384
    unsigned* packed = (unsigned*)(Bpkf + 16384);   // NE u32
    int* col    = (int*)(packed + NE);              // NE
    int* rowptr = col + NE;                         // NN+1
    int* bcnt   = rowptr + NN + 1;                  // NBUCK
    int* bbase  = bcnt + NBUCK;                     // NBUCK
    int* bcur   = bbase + NBUCK;                    // NBUCK

    dim3 blk(256);
    int gemmBlocks = (NN + 127) / 128;   // 391
    int prepBlocks = CONVB + 320 + 1;    // conv + pack0 + pack1 + packf + zero

    // fused prep (conv + weight packs + bcnt zero)
    prep_kernel<<<prepBlocks, blk, 0, stream>>>(
        (const float4*)x, (ushort4*)hb0, Wl, Wr, W, Bpk0, Bpk1, Bpkf, bcnt);

    // CSR build via bucketed counting sort
    bucket_hist<<<PBLOCKS, blk, 0, stream>>>(ei, bcnt);
    bucket_scan<<<1, blk, 0, stream>>>(bcnt, bbase, bcur, rowptr);
    bucket_partition<<<PBLOCKS, blk, 0, stream>>>(ei, bcur, packed);
    bucket_csr<<<NBUCK, blk, 0, stream>>>(packed, bcnt, bbase, rowptr, col);

    // Layer 0: agg fused into GEMM, out -> hb1 (relu bf16)
    fused_layer<false><<<gemmBlocks, blk, 0, stream>>>(
        hb0, rowptr, col, Bpk0, bl, nullptr, nullptr, hb1);

    // Layer 1 + final linear fused: agg -> GEMM(relu->LDS) -> GEMM -> fp32 out
    fused_layer<true><<<gemmBlocks, blk, 0, stream>>>(
        hb1, rowptr, col, Bpk1, bl + DD, Bpkf, b, out);
}

// Round 3
// 235.759 us; speedup vs baseline: 1.0512x; 1.0512x over previous
//
#include <hip/hip_runtime.h>
#include <math.h>

#define NN 50000
#define NE 800000
#define DD 128
#define NBUCK 196        // ceil(NN/256) buckets of 256 nodes
#define EPB 2048         // edges per hist/partition block
#define PB 391           // ceil(NE/EPB)
#define CONVB 6250       // NN*DD/4/256

typedef unsigned short u16;
typedef short s8v __attribute__((ext_vector_type(8)));    // 8 bf16 (4 VGPRs)
typedef float f16v __attribute__((ext_vector_type(16)));  // 16 fp32 acc

__device__ __forceinline__ u16 f2bf(float f) {  // RNE fp32->bf16
    unsigned u = __float_as_uint(f);
    return (u16)((u + 0x7FFFu + ((u >> 16) & 1u)) >> 16);
}
__device__ __forceinline__ float bflo(unsigned u) { return __uint_as_float(u << 16); }
__device__ __forceinline__ float bfhi(unsigned u) { return __uint_as_float(u & 0xFFFF0000u); }

// ---- zero bcnt + claim (replaces hipMemsetAsync: keep launch graph-capture-safe) ----
__global__ __launch_bounds__(256) void zero_kernel(int* __restrict__ p, int n) {
    int i = threadIdx.x + blockIdx.x * 256;
    if (i < n) p[i] = 0;
}

// ---- fused prep: x->bf16 conv | 3x weight pack | edge histogram ----
// pack order: out[((c*4+n)*64+l)*8+j] = Wcat[col=n*32+(l&31)][k=c*16+(l>>5)*8+j]
__device__ __forceinline__ void pack_one(const float* __restrict__ Wl,
                                         const float* __restrict__ Wr,
                                         bool two, int o, u16* __restrict__ out) {
    int j = o & 7;
    int l = (o >> 3) & 63;
    int cn = o >> 9;
    int n = cn & 3;
    int c = cn >> 2;
    int colj = n * 32 + (l & 31);
    int k = c * 16 + (l >> 5) * 8 + j;
    float v;
    if (two) v = (k < DD) ? Wl[colj * DD + k] : Wr[colj * DD + (k - DD)];
    else     v = Wl[colj * DD + k];
    out[o] = f2bf(v);
}

__global__ __launch_bounds__(256) void prep_kernel(
        const float4* __restrict__ x4, ushort4* __restrict__ hb0,
        const float* __restrict__ Wl, const float* __restrict__ Wr,
        const float* __restrict__ W,
        u16* __restrict__ Bpk0, u16* __restrict__ Bpk1, u16* __restrict__ Bpkf,
        const int* __restrict__ ei, int* __restrict__ bcnt) {
    int bid = blockIdx.x;
    int tid = threadIdx.x;
    if (bid < CONVB) {
        int i = bid * 256 + tid;
        float4 v = x4[i];
        ushort4 o;
        o.x = f2bf(v.x); o.y = f2bf(v.y); o.z = f2bf(v.z); o.w = f2bf(v.w);
        hb0[i] = o;
    } else if (bid < CONVB + 128) {
        pack_one(Wl, Wr, true, (bid - CONVB) * 256 + tid, Bpk0);
    } else if (bid < CONVB + 256) {
        pack_one(Wl + DD * DD, Wr + DD * DD, true, (bid - CONVB - 128) * 256 + tid, Bpk1);
    } else if (bid < CONVB + 320) {
        pack_one(W, W, false, (bid - CONVB - 256) * 256 + tid, Bpkf);
    } else {
        // coarse bucket histogram (bcnt zeroed by zero_kernel)
        __shared__ int h[NBUCK];
        for (int i = tid; i < NBUCK; i += 256) h[i] = 0;
        __syncthreads();
        int e0 = (bid - (CONVB + 320)) * EPB;
#pragma unroll
        for (int i = 0; i < 8; i++) {
            int e = e0 + i * 256 + tid;
            if (e < NE) atomicAdd(&h[ei[NE + e] >> 8], 1);
        }
        __syncthreads();
        for (int i = tid; i < NBUCK; i += 256)
            if (h[i]) atomicAdd(&bcnt[i], h[i]);
    }
}

// ---- partition edges into bucket-contiguous packed array ----
// Each block recomputes the 196-entry exclusive scan of bcnt locally; global
// cursor comes from zero-initialized claim[] (bb[bk] + atomicAdd(claim[bk],c)).
__global__ __launch_bounds__(256) void bucket_partition(const int* __restrict__ ei,
                                                        const int* __restrict__ bcnt,
                                                        int* __restrict__ claim,
                                                        unsigned* __restrict__ packed,
                                                        int* __restrict__ rowptr) {
    __shared__ int sc[256];
    __shared__ int bb[NBUCK];
    __shared__ int h[NBUCK];
    __shared__ int base[NBUCK];
    int t = threadIdx.x;
    int v = (t < NBUCK) ? bcnt[t] : 0;
    sc[t] = v;
    __syncthreads();
    for (int o = 1; o < 256; o <<= 1) {
        int u = (t >= o) ? sc[t - o] : 0;
        __syncthreads();
        sc[t] += u;
        __syncthreads();
    }
    if (t < NBUCK) bb[t] = sc[t] - v;
    if (t == 0 && blockIdx.x == 0) rowptr[NN] = NE;
    for (int i = t; i < NBUCK; i += 256) h[i] = 0;
    __syncthreads();
    int e0 = blockIdx.x * EPB;
    int dsts[8], srcs[8];
#pragma unroll
    for (int i = 0; i < 8; i++) {
        int e = e0 + i * 256 + t;
        if (e < NE) {
            dsts[i] = ei[NE + e];
            srcs[i] = ei[e];
            atomicAdd(&h[dsts[i] >> 8], 1);
        } else dsts[i] = -1;
    }
    __syncthreads();
    for (int i = t; i < NBUCK; i += 256) {
        int c = h[i];
        base[i] = c ? bb[i] + atomicAdd(&claim[i], c) : 0;
    }
    __syncthreads();
    for (int i = t; i < NBUCK; i += 256) h[i] = 0;  // reuse as local cursor
    __syncthreads();
#pragma unroll
    for (int i = 0; i < 8; i++) {
        if (dsts[i] >= 0) {
            int bk = dsts[i] >> 8;
            int r = atomicAdd(&h[bk], 1);
            packed[base[bk] + r] = (unsigned)srcs[i] | ((unsigned)(dsts[i] & 255) << 16);
        }
    }
}

// ---- per-bucket counting sort -> rowptr + col (recomputes bucket bases) ----
__global__ __launch_bounds__(256) void bucket_csr(const unsigned* __restrict__ packed,
                                                  const int* __restrict__ bcnt,
                                                  int* __restrict__ rowptr,
                                                  int* __restrict__ col) {
    __shared__ int sc[256];
    __shared__ int deg[256];
    __shared__ int off[256];
    int t = threadIdx.x;
    int v0 = (t < NBUCK) ? bcnt[t] : 0;
    sc[t] = v0;
    __syncthreads();
    for (int o = 1; o < 256; o <<= 1) {
        int u = (t >= o) ? sc[t - o] : 0;
        __syncthreads();
        sc[t] += u;
        __syncthreads();
    }
    int bk = blockIdx.x;
    int cnt = bcnt[bk];
    int base = sc[bk] - cnt;  // exclusive scan value for this bucket
    deg[t] = 0;
    __syncthreads();
    for (int i = t; i < cnt; i += 256) atomicAdd(&deg[packed[base + i] >> 16], 1);
    __syncthreads();
    int v = deg[t];
    off[t] = v;
    __syncthreads();
    for (int o = 1; o < 256; o <<= 1) {
        int u = (t >= o) ? off[t - o] : 0;
        __syncthreads();
        off[t] += u;
        __syncthreads();
    }
    int ex = off[t] - v;
    int node = (bk << 8) + t;
    if (node < NN) rowptr[node] = base + ex;
    deg[t] = ex;  // reuse as cursor
    __syncthreads();
    for (int i = t; i < cnt; i += 256) {
        unsigned p = packed[base + i];
        int dl = p >> 16;
        int r = atomicAdd(&deg[dl], 1);
        col[base + r] = (int)(p & 0xFFFFu);
    }
}

// ---- segmented max on bf16 (CSR), 16 lanes/node, 16B/lane, unroll-8 ----
__device__ __forceinline__ void vmax8(float* m, uint4 v) {
    m[0] = fmaxf(m[0], bflo(v.x)); m[1] = fmaxf(m[1], bfhi(v.x));
    m[2] = fmaxf(m[2], bflo(v.y)); m[3] = fmaxf(m[3], bfhi(v.y));
    m[4] = fmaxf(m[4], bflo(v.z)); m[5] = fmaxf(m[5], bfhi(v.z));
    m[6] = fmaxf(m[6], bflo(v.w)); m[7] = fmaxf(m[7], bfhi(v.w));
}

__global__ __launch_bounds__(256) void agg_kernel_bf(const uint4* __restrict__ xb4,
                                                     const int* __restrict__ row_ptr,
                                                     const int* __restrict__ col,
                                                     uint4* __restrict__ aggb4) {
    int node = blockIdx.x * 16 + (threadIdx.x >> 4);
    if (node >= NN) return;
    int j = threadIdx.x & 15;
    int s0 = row_ptr[node], s1 = row_ptr[node + 1];
    if (s0 == s1) {
        aggb4[(size_t)node * 16 + j] = make_uint4(0, 0, 0, 0);
        return;
    }
    float m0[8], m1[8], m2[8], m3[8];
#pragma unroll
    for (int q = 0; q < 8; q++) { m0[q] = m1[q] = m2[q] = m3[q] = -INFINITY; }
    int i = s0;
    for (; i + 8 <= s1; i += 8) {
        int c0 = col[i],     c1 = col[i + 1], c2 = col[i + 2], c3 = col[i + 3];
        int c4 = col[i + 4], c5 = col[i + 5], c6 = col[i + 6], c7 = col[i + 7];
        uint4 v0 = xb4[(size_t)c0 * 16 + j];
        uint4 v1 = xb4[(size_t)c1 * 16 + j];
        uint4 v2 = xb4[(size_t)c2 * 16 + j];
        uint4 v3 = xb4[(size_t)c3 * 16 + j];
        uint4 v4 = xb4[(size_t)c4 * 16 + j];
        uint4 v5 = xb4[(size_t)c5 * 16 + j];
        uint4 v6 = xb4[(size_t)c6 * 16 + j];
        uint4 v7 = xb4[(size_t)c7 * 16 + j];
        vmax8(m0, v0); vmax8(m1, v1); vmax8(m2, v2); vmax8(m3, v3);
        vmax8(m0, v4); vmax8(m1, v5); vmax8(m2, v6); vmax8(m3, v7);
    }
    for (; i + 4 <= s1; i += 4) {
        int c0 = col[i], c1 = col[i + 1], c2 = col[i + 2], c3 = col[i + 3];
        uint4 v0 = xb4[(size_t)c0 * 16 + j];
        uint4 v1 = xb4[(size_t)c1 * 16 + j];
        uint4 v2 = xb4[(size_t)c2 * 16 + j];
        uint4 v3 = xb4[(size_t)c3 * 16 + j];
        vmax8(m0, v0); vmax8(m1, v1); vmax8(m2, v2); vmax8(m3, v3);
    }
    for (; i < s1; i++) {
        uint4 v = xb4[(size_t)col[i] * 16 + j];
        vmax8(m0, v);
    }
#pragma unroll
    for (int q = 0; q < 8; q++) m0[q] = fmaxf(fmaxf(m0[q], m1[q]), fmaxf(m2[q], m3[q]));
    uint4 o;  // values are exact bf16 -> pack by truncation
    o.x = (__float_as_uint(m0[0]) >> 16) | (__float_as_uint(m0[1]) & 0xFFFF0000u);
    o.y = (__float_as_uint(m0[2]) >> 16) | (__float_as_uint(m0[3]) & 0xFFFF0000u);
    o.z = (__float_as_uint(m0[4]) >> 16) | (__float_as_uint(m0[5]) & 0xFFFF0000u);
    o.w = (__float_as_uint(m0[6]) >> 16) | (__float_as_uint(m0[7]) & 0xFFFF0000u);
    aggb4[(size_t)node * 16 + j] = o;
}

// ---------------- MFMA GEMM (no LDS: B-fragments straight from L2) ----------------
// out[row][col] = bias[col] + sum_k A[row][k] * Wcat[col][k]
// A = [srcA | srcB] (K=256). 128 rows x 128 cols / block. Layer-0 variant.
__global__ __launch_bounds__(256) void mfma_gemm0(const u16* __restrict__ srcA,
                                                  const u16* __restrict__ srcB,
                                                  const u16* __restrict__ Bpk,
                                                  const float* __restrict__ bias,
                                                  u16* __restrict__ outh) {
    int tid = threadIdx.x;
    int wt = tid >> 6;
    int lane = tid & 63;
    int row0 = blockIdx.x * 128 + wt * 32;
    int rload = row0 + (lane & 31);
    if (rload > NN - 1) rload = NN - 1;  // clamp OOB loads
    int koff = (lane >> 5) * 8;
    const s8v* Bv = (const s8v*)Bpk;

    f16v acc[4];
#pragma unroll
    for (int n = 0; n < 4; n++) acc[n] = (f16v)(0.0f);

#pragma unroll
    for (int c = 0; c < 16; c++) {
        const u16* s = srcA;
        int kk = c * 16;
        if (c >= 8) { s = srcB; kk = (c - 8) * 16; }
        s8v a = *(const s8v*)(s + (size_t)rload * DD + kk + koff);
#pragma unroll
        for (int n = 0; n < 4; n++) {
            s8v b = Bv[(c * 4 + n) * 64 + lane];
            acc[n] = __builtin_amdgcn_mfma_f32_32x32x16_bf16(a, b, acc[n], 0, 0, 0);
        }
    }

    // epilogue: C/D layout col=lane&31, row=(reg&3)+8*(reg>>2)+4*(lane>>5)
    int rowadd = 4 * (lane >> 5);
#pragma unroll
    for (int n = 0; n < 4; n++) {
        int colj = n * 32 + (lane & 31);
        float bj = bias[colj];
#pragma unroll
        for (int r = 0; r < 16; r++) {
            int row = row0 + (r & 3) + 8 * (r >> 2) + rowadd;
            if (row < NN)
                outh[(size_t)row * DD + colj] = f2bf(fmaxf(acc[n][r] + bj, 0.0f));
        }
    }
}

// ---- layer-1 GEMM + final linear fused: relu bf16 tile -> LDS -> 2nd MFMA ----
__global__ __launch_bounds__(256) void gemm_final(const u16* __restrict__ srcA,
                                                  const u16* __restrict__ srcB,
                                                  const u16* __restrict__ Bpk,
                                                  const float* __restrict__ bias,
                                                  const u16* __restrict__ Bpkf,
                                                  const float* __restrict__ bfin,
                                                  float* __restrict__ out) {
    __shared__ u16 As[128 * 128];  // 32 KB, XOR-swizzled rows
    char* Ab = (char*)As;
    int tid = threadIdx.x;
    int wt = tid >> 6;
    int lane = tid & 63;
    int row0 = blockIdx.x * 128;
    int arl = wt * 32 + (lane & 31);
    int rg = row0 + arl;
    if (rg > NN - 1) rg = NN - 1;
    int koff = (lane >> 5) * 8;
    int swz = (arl & 7) << 4;
    const s8v* Bv = (const s8v*)Bpk;

    f16v acc[4];
#pragma unroll
    for (int n = 0; n < 4; n++) acc[n] = (f16v)(0.0f);

#pragma unroll
    for (int c = 0; c < 16; c++) {
        const u16* s = srcA;
        int kk = c * 16;
        if (c >= 8) { s = srcB; kk = (c - 8) * 16; }
        s8v a = *(const s8v*)(s + (size_t)rg * DD + kk + koff);
#pragma unroll
        for (int n = 0; n < 4; n++) {
            s8v b = Bv[(c * 4 + n) * 64 + lane];
            acc[n] = __builtin_amdgcn_mfma_f32_32x32x16_bf16(a, b, acc[n], 0, 0, 0);
        }
    }

    // relu'd bf16 acc -> LDS (this tile IS the A-operand of the final linear)
    int rowadd = 4 * (lane >> 5);
#pragma unroll
    for (int n = 0; n < 4; n++) {
        int colj = n * 32 + (lane & 31);
        float bj = bias[colj];
#pragma unroll
        for (int r = 0; r < 16; r++) {
            int rloc = wt * 32 + (r & 3) + 8 * (r >> 2) + rowadd;
            float v = fmaxf(acc[n][r] + bj, 0.0f);
            *(u16*)(Ab + rloc * 256 + ((colj * 2) ^ ((rloc & 7) << 4))) = f2bf(v);
        }
    }
    __syncthreads();

    // final GEMM: K=128 from LDS, B = Bpkf
    const s8v* Bvf = (const s8v*)Bpkf;
    f16v acc2[4];
#pragma unroll
    for (int n = 0; n < 4; n++) acc2[n] = (f16v)(0.0f);
#pragma unroll
    for (int c = 0; c < 8; c++) {
        s8v a = *(const s8v*)(Ab + arl * 256 + (((c * 16 + koff) * 2) ^ swz));
#pragma unroll
        for (int n = 0; n < 4; n++) {
            s8v b = Bvf[(c * 4 + n) * 64 + lane];
            acc2[n] = __builtin_amdgcn_mfma_f32_32x32x16_bf16(a, b, acc2[n], 0, 0, 0);
        }
    }
#pragma unroll
    for (int n = 0; n < 4; n++) {
        int colj = n * 32 + (lane & 31);
        float bj = bfin[colj];
#pragma unroll
        for (int r = 0; r < 16; r++) {
            int row = row0 + wt * 32 + (r & 3) + 8 * (r >> 2) + rowadd;
            if (row < NN)
                out[(size_t)row * DD + colj] = acc2[n][r] + bj;
        }
    }
}

extern "C" void kernel_launch(void* const* d_in, const int* in_sizes, int n_in,
                              void* d_out, int out_size, void* d_ws, size_t ws_size,
                              hipStream_t stream) {
    const float* x  = (const float*)d_in[0];
    const int*   ei = (const int*)d_in[1];
    const float* Wl = (const float*)d_in[2];
    const float* bl = (const float*)d_in[3];
    const float* Wr = (const float*)d_in[4];
    const float* W  = (const float*)d_in[5];
    const float* b  = (const float*)d_in[6];
    float* out = (float*)d_out;

    // ws layout (16B-aligned chunks)
    u16* aggb = (u16*)d_ws;                         // NN*DD bf16
    u16* hb0  = aggb + (size_t)NN * DD;             // NN*DD
    u16* hb1  = hb0 + (size_t)NN * DD;              // NN*DD
    u16* Bpk0 = hb1 + (size_t)NN * DD;              // 32768
    u16* Bpk1 = Bpk0 + 32768;                       // 32768
    u16* Bpkf = Bpk1 + 32768;                       // 16384
    unsigned* packed = (unsigned*)(Bpkf + 16384);   // NE u32
    int* col    = (int*)(packed + NE);              // NE
    int* rowptr = col + NE;                         // NN+1
    int* bcnt   = rowptr + NN + 1;                  // NBUCK
    int* claim  = bcnt + NBUCK;                     // NBUCK

    dim3 blk(256);
    int gemmBlocks = (NN + 127) / 128;   // 391
    int aggBlocks  = (NN + 15) / 16;     // 3125
    int prepBlocks = CONVB + 320 + PB;   // conv + 3 packs + hist

    // zero bcnt+claim (graph-capture-safe), then fused prep (conv | packs | hist)
    zero_kernel<<<2, blk, 0, stream>>>(bcnt, 2 * NBUCK);
    prep_kernel<<<prepBlocks, blk, 0, stream>>>(
        (const float4*)x, (ushort4*)hb0, Wl, Wr, W, Bpk0, Bpk1, Bpkf, ei, bcnt);

    // CSR build (scan folded into partition/csr via local scans + claim[])
    bucket_partition<<<PB, blk, 0, stream>>>(ei, bcnt, claim, packed, rowptr);
    bucket_csr<<<NBUCK, blk, 0, stream>>>(packed, bcnt, rowptr, col);

    // Layer 0
    agg_kernel_bf<<<aggBlocks, blk, 0, stream>>>((const uint4*)hb0, rowptr, col, (uint4*)aggb);
    mfma_gemm0<<<gemmBlocks, blk, 0, stream>>>(aggb, hb0, Bpk0, bl, hb1);

    // Layer 1 + final linear fused
    agg_kernel_bf<<<aggBlocks, blk, 0, stream>>>((const uint4*)hb1, rowptr, col, (uint4*)aggb);
    gemm_final<<<gemmBlocks, blk, 0, stream>>>(aggb, hb1, Bpk1, bl + DD, Bpkf, b, out);
}